// Round 11
// baseline (516.972 us; speedup 1.0000x reference)
//
#include <hip/hip_runtime.h>
#include <math.h>

// ---------------------------------------------------------------------------
// DecoderLayer fused implementation (MI355X / gfx950)
//   K0: convert weights fp32 -> bf16 into ws (layouts already [n][k] row-major)
//   K1: FULLY FUSED per-node layer: message MLP (3 GEMMs) + edge-sum + LN1
//       + FFN (128->512->128) + LN2 + mask_V, 2 nodes/block, 256 threads,
//       2048 blocks. Phase 1 = R5's best-measured pipeline (LDS dbuf staging,
//       1 raw s_barrier/step, W-before-E issue order). The FFN tail rides in
//       msg's latency slack (counters showed MfmaUtil<9%, VALU<26%) --
//       deleting the separate ffn_kernel removes its ~90us of latency-bound
//       time for ~15us of added L2 traffic.
//   Tail LDS layout (all in the dead staging arena, fenced by syncthreads):
//       a2  @ 0      (16x136 bf16, rows mirror hn[r&1])
//       ff  @ 4352   (16x520 bf16)
//       tb  @ 20992  (2x132 fp32)
//       tbuf@ 27648  (256 fp32, pre-LN1 values)
//       hn  @ 28672  (2x128 fp32, LN1 output; also FFN residual)
// ---------------------------------------------------------------------------

typedef __bf16 bf16;
typedef __attribute__((ext_vector_type(8))) __bf16 bf16x8;
typedef __attribute__((ext_vector_type(4))) __bf16 bf16x4;
typedef __attribute__((ext_vector_type(4))) float f32x4;

__device__ __forceinline__ bf16 f2bf(float f) {
    unsigned u = __builtin_bit_cast(unsigned, f);
    u += 0x7FFFu + ((u >> 16) & 1u);           // RTNE
    unsigned short s = (unsigned short)(u >> 16);
    return __builtin_bit_cast(bf16, s);
}

// pack two fp32 -> two bf16 (RTNE), one instruction
__device__ __forceinline__ unsigned cvt_pk_bf16(float lo, float hi) {
    unsigned r;
    asm("v_cvt_pk_bf16_f32 %0, %1, %2" : "=v"(r) : "v"(lo), "v"(hi));
    return r;
}

__device__ __forceinline__ float gelu_exact(float x) {
    return 0.5f * x * (1.0f + erff(x * 0.70710678118654752f));
}

__device__ __forceinline__ f32x4 mfma16(bf16x8 a, bf16x8 b, f32x4 c) {
    return __builtin_amdgcn_mfma_f32_16x16x32_bf16(a, b, c, 0, 0, 0);
}

// ws layout (bf16 elements):
#define WS_W2   65536
#define WS_W3   81920
#define WS_WIN  98304
#define WS_WOUT 163840
#define WS_TOTAL_W 229376

// ---------------------------------------------------------------------------
__global__ void convert_weights(const float* __restrict__ W1, const float* __restrict__ W2,
                                const float* __restrict__ W3, const float* __restrict__ Win,
                                const float* __restrict__ Wout, bf16* __restrict__ ws) {
    int i = blockIdx.x * 256 + threadIdx.x;
    if (i < WS_W2)              ws[i] = f2bf(W1[i]);
    else if (i < WS_W3)         ws[i] = f2bf(W2[i - WS_W2]);
    else if (i < WS_WIN)        ws[i] = f2bf(W3[i - WS_W3]);
    else if (i < WS_WOUT)       ws[i] = f2bf(Win[i - WS_WIN]);
    else if (i < WS_TOTAL_W)    ws[i] = f2bf(Wout[i - WS_WOUT]);
}

// ---------------------------------------------------------------------------
// K1: fully fused layer. 2 nodes per block (M = 96 rows), 256 threads.
__global__ __launch_bounds__(256, 3)
void msg_kernel(const float* __restrict__ h_V, const float* __restrict__ h_E,
                const float* __restrict__ mask_attend,
                const bf16* __restrict__ W1b, const bf16* __restrict__ W2b,
                const bf16* __restrict__ W3b,
                const float* __restrict__ b1, const float* __restrict__ b2,
                const float* __restrict__ b3,
                const float* __restrict__ ln1g, const float* __restrict__ ln1b,
                const bf16* __restrict__ Winb, const bf16* __restrict__ Woutb,
                const float* __restrict__ bin, const float* __restrict__ bout,
                const float* __restrict__ ln2g, const float* __restrict__ ln2b,
                const float* __restrict__ mask_V, float* __restrict__ out) {
    __shared__ __align__(16) char smem[53760];
    bf16*  st0  = (bf16*)smem;              // 96 x 72   (phase-1 staging)
    bf16*  st1  = (bf16*)(smem + 13824);    // 96 x 72
    bf16*  m2   = (bf16*)smem;              // 96 x 136  (aliases st0+st1)
    bf16*  m1   = (bf16*)(smem + 27648);    // 96 x 136
    // tail (all after phase-3 m2 reads, fenced):
    bf16*  a2   = (bf16*)smem;              // 16 x 136 @ 0
    bf16*  ff   = (bf16*)(smem + 4352);     // 16 x 520
    float* tb   = (float*)(smem + 20992);   // 2 x 132
    float* tbuf = (float*)(smem + 27648);   // 256 fp32 (aliases m1, dead)
    float* hn   = (float*)(smem + 28672);   // 2 x 128 fp32 (aliases m1, dead)

    const int tid  = threadIdx.x;
    const int wave = tid >> 6;
    const int lane = tid & 63;
    const int q    = lane >> 4;     // quad 0..3
    const int c15  = lane & 15;
    const int g0   = blockIdx.x * 2;  // first node of this block
    const int wcol0 = wave * 32 + c15;
    const int wcol1 = wcol0 + 16;

    const int r0  = tid >> 4;   // staging row within 16-row group
    const int l16 = tid & 15;   // staging float4 index

    f32x4 zero = {0.f, 0.f, 0.f, 0.f};
    f32x4 acc[6][2];
#pragma unroll
    for (int mt = 0; mt < 6; ++mt) { acc[mt][0] = zero; acc[mt][1] = zero; }

#define STAGE_LOAD(dst_, kb_)                                                   \
    {                                                                           \
        _Pragma("unroll")                                                       \
        for (int it = 0; it < 6; ++it) {                                        \
            const int row_ = it * 16 + r0;                                      \
            const int nl_  = row_ >= 48;                                        \
            const float* src_ = ((kb_) < 2)                                     \
                ? (h_V + (size_t)(g0 + nl_) * 128 + (kb_) * 64 + l16 * 4)       \
                : (h_E + (size_t)((g0 + nl_) * 48 + row_ - 48 * nl_) * 384 + (kb_) * 64 - 128 + l16 * 4); \
            dst_[it] = *(const float4*)src_;                                    \
        }                                                                       \
    }

#define STAGE_WRITE(buf_, src_)                                                 \
    {                                                                           \
        _Pragma("unroll")                                                       \
        for (int it = 0; it < 6; ++it) {                                        \
            const int row_ = it * 16 + r0;                                      \
            uint2 w_;                                                           \
            w_.x = cvt_pk_bf16(src_[it].x, src_[it].y);                         \
            w_.y = cvt_pk_bf16(src_[it].z, src_[it].w);                         \
            *(uint2*)((buf_) + row_ * 72 + l16 * 4) = w_;                       \
        }                                                                       \
    }

#define LD_W(w00_, w01_, w10_, w11_, kb_)                                       \
    {                                                                           \
        w00_ = *(const bf16x8*)(W1b + (size_t)wcol0 * 512 + (kb_) * 64 + q * 8);      \
        w01_ = *(const bf16x8*)(W1b + (size_t)wcol0 * 512 + (kb_) * 64 + 32 + q * 8); \
        w10_ = *(const bf16x8*)(W1b + (size_t)wcol1 * 512 + (kb_) * 64 + q * 8);      \
        w11_ = *(const bf16x8*)(W1b + (size_t)wcol1 * 512 + (kb_) * 64 + 32 + q * 8); \
    }

#define MFMA_STEP(stb_, w00_, w01_, w10_, w11_)                                 \
    {                                                                           \
        __builtin_amdgcn_s_setprio(1);                                          \
        _Pragma("unroll")                                                       \
        for (int mt = 0; mt < 6; ++mt) {                                        \
            bf16x8 a0_ = *(const bf16x8*)((stb_) + (mt * 16 + c15) * 72 + q * 8);      \
            bf16x8 a1_ = *(const bf16x8*)((stb_) + (mt * 16 + c15) * 72 + 32 + q * 8); \
            acc[mt][0] = mfma16(a0_, w00_, acc[mt][0]);                         \
            acc[mt][0] = mfma16(a1_, w01_, acc[mt][0]);                         \
            acc[mt][1] = mfma16(a0_, w10_, acc[mt][1]);                         \
            acc[mt][1] = mfma16(a1_, w11_, acc[mt][1]);                         \
        }                                                                       \
        __builtin_amdgcn_s_setprio(0);                                          \
    }

    // raw barrier: drain only LDS ops; global loads stay in flight (no vmcnt!)
#define BAR() { asm volatile("s_waitcnt lgkmcnt(0)" ::: "memory"); __builtin_amdgcn_s_barrier(); }

    // ---------------- phase 1 (R5 pipeline, unchanged) ----------------
    {
        float4 rA[6], rB[6];
        bf16x8 wc0, wc1, wc2, wc3, wn0, wn1, wn2, wn3;

        STAGE_LOAD(rA, 0);              // E(0)
        LD_W(wc0, wc1, wc2, wc3, 0);    // W(0)  (before E(1))
        STAGE_LOAD(rB, 1);              // E(1)
        STAGE_WRITE(st0, rA);           // waits E(0) only
        BAR();
        LD_W(wn0, wn1, wn2, wn3, 1);
        STAGE_LOAD(rA, 2);
        MFMA_STEP(st0, wc0, wc1, wc2, wc3);
        STAGE_WRITE(st1, rB);
        BAR();
        LD_W(wc0, wc1, wc2, wc3, 2);
        STAGE_LOAD(rB, 3);
        MFMA_STEP(st1, wn0, wn1, wn2, wn3);
        STAGE_WRITE(st0, rA);
        BAR();
        LD_W(wn0, wn1, wn2, wn3, 3);
        STAGE_LOAD(rA, 4);
        MFMA_STEP(st0, wc0, wc1, wc2, wc3);
        STAGE_WRITE(st1, rB);
        BAR();
        LD_W(wc0, wc1, wc2, wc3, 4);
        STAGE_LOAD(rB, 5);
        MFMA_STEP(st1, wn0, wn1, wn2, wn3);
        STAGE_WRITE(st0, rA);
        BAR();
        LD_W(wn0, wn1, wn2, wn3, 5);
        STAGE_LOAD(rA, 6);
        MFMA_STEP(st0, wc0, wc1, wc2, wc3);
        STAGE_WRITE(st1, rB);
        BAR();
        LD_W(wc0, wc1, wc2, wc3, 6);
        STAGE_LOAD(rB, 7);
        MFMA_STEP(st1, wn0, wn1, wn2, wn3);
        STAGE_WRITE(st0, rA);
        BAR();
        LD_W(wn0, wn1, wn2, wn3, 7);
        MFMA_STEP(st0, wc0, wc1, wc2, wc3);
        STAGE_WRITE(st1, rB);
        BAR();
        MFMA_STEP(st1, wn0, wn1, wn2, wn3);
    }
#undef BAR
#undef MFMA_STEP
#undef LD_W
#undef STAGE_WRITE
#undef STAGE_LOAD

    // epilogue 1: bias + gelu -> m1   (C/D layout: row = q*4+reg, col = c15)
    {
        const float bb0 = b1[wcol0];
        const float bb1 = b1[wcol1];
#pragma unroll
        for (int mt = 0; mt < 6; ++mt) {
#pragma unroll
            for (int r = 0; r < 4; ++r) {
                const int row = mt * 16 + q * 4 + r;
                m1[row * 136 + wcol0] = f2bf(gelu_exact(acc[mt][0][r] + bb0));
                m1[row * 136 + wcol1] = f2bf(gelu_exact(acc[mt][1][r] + bb1));
            }
        }
    }
    __syncthreads();

    // ---------------- phase 2 ----------------
#pragma unroll
    for (int mt = 0; mt < 6; ++mt) { acc[mt][0] = zero; acc[mt][1] = zero; }
    __builtin_amdgcn_s_setprio(1);
#pragma unroll
    for (int s = 0; s < 4; ++s) {
        const bf16x8 w0 = *(const bf16x8*)(W2b + (size_t)wcol0 * 128 + s * 32 + q * 8);
        const bf16x8 w1 = *(const bf16x8*)(W2b + (size_t)wcol1 * 128 + s * 32 + q * 8);
#pragma unroll
        for (int mt = 0; mt < 6; ++mt) {
            bf16x8 af = *(const bf16x8*)(m1 + (mt * 16 + c15) * 136 + s * 32 + q * 8);
            acc[mt][0] = mfma16(af, w0, acc[mt][0]);
            acc[mt][1] = mfma16(af, w1, acc[mt][1]);
        }
    }
    __builtin_amdgcn_s_setprio(0);
    {
        const float bb0 = b2[wcol0];
        const float bb1 = b2[wcol1];
#pragma unroll
        for (int mt = 0; mt < 6; ++mt) {
#pragma unroll
            for (int r = 0; r < 4; ++r) {
                const int row = mt * 16 + q * 4 + r;
                m2[row * 136 + wcol0] = f2bf(gelu_exact(acc[mt][0][r] + bb0));
                m2[row * 136 + wcol1] = f2bf(gelu_exact(acc[mt][1][r] + bb1));
            }
        }
    }
    __syncthreads();

    // ---------------- phase 3 ----------------
#pragma unroll
    for (int mt = 0; mt < 6; ++mt) { acc[mt][0] = zero; acc[mt][1] = zero; }
    __builtin_amdgcn_s_setprio(1);
#pragma unroll
    for (int s = 0; s < 4; ++s) {
        const bf16x8 w0 = *(const bf16x8*)(W3b + (size_t)wcol0 * 128 + s * 32 + q * 8);
        const bf16x8 w1 = *(const bf16x8*)(W3b + (size_t)wcol1 * 128 + s * 32 + q * 8);
#pragma unroll
        for (int mt = 0; mt < 6; ++mt) {
            bf16x8 af = *(const bf16x8*)(m2 + (mt * 16 + c15) * 136 + s * 32 + q * 8);
            acc[mt][0] = mfma16(af, w0, acc[mt][0]);
            acc[mt][1] = mfma16(af, w1, acc[mt][1]);
        }
    }
    __builtin_amdgcn_s_setprio(0);
    // masked sum over edges -> tbuf (pre-LN1 values)
    {
        const float bb0 = b3[wcol0];
        const float bb1 = b3[wcol1];
        float s00 = 0.f, s01 = 0.f, s10 = 0.f, s11 = 0.f;
#pragma unroll
        for (int mt = 0; mt < 6; ++mt) {
#pragma unroll
            for (int r = 0; r < 4; ++r) {
                const int row = mt * 16 + q * 4 + r;
                const int nl  = row >= 48;
                const float mv = mask_attend[(size_t)(g0 + nl) * 48 + row - 48 * nl];
                const float v0 = (acc[mt][0][r] + bb0) * mv;
                const float v1 = (acc[mt][1][r] + bb1) * mv;
                if (nl) { s10 += v0; s11 += v1; } else { s00 += v0; s01 += v1; }
            }
        }
#pragma unroll
        for (int off = 16; off <= 32; off <<= 1) {
            s00 += __shfl_xor(s00, off);
            s01 += __shfl_xor(s01, off);
            s10 += __shfl_xor(s10, off);
            s11 += __shfl_xor(s11, off);
        }
        if (lane < 16) {
            tbuf[wcol0]       = h_V[(size_t)g0 * 128 + wcol0]       + s00 * (1.0f / 30.0f);
            tbuf[wcol1]       = h_V[(size_t)g0 * 128 + wcol1]       + s01 * (1.0f / 30.0f);
            tbuf[128 + wcol0] = h_V[(size_t)(g0 + 1) * 128 + wcol0] + s10 * (1.0f / 30.0f);
            tbuf[128 + wcol1] = h_V[(size_t)(g0 + 1) * 128 + wcol1] + s11 * (1.0f / 30.0f);
        }
    }
    __syncthreads();
    // LN1 -> hn (LDS), no global round-trip
    if (wave < 2) {
        const float x0 = tbuf[wave * 128 + lane];
        const float x1 = tbuf[wave * 128 + 64 + lane];
        float sm = x0 + x1, sq = x0 * x0 + x1 * x1;
#pragma unroll
        for (int off = 1; off < 64; off <<= 1) { sm += __shfl_xor(sm, off); sq += __shfl_xor(sq, off); }
        const float mu  = sm * (1.0f / 128.0f);
        const float var = sq * (1.0f / 128.0f) - mu * mu;
        const float inv = rsqrtf(var + 1e-5f);
        hn[wave * 128 + lane]      = (x0 - mu) * inv * ln1g[lane]      + ln1b[lane];
        hn[wave * 128 + 64 + lane] = (x1 - mu) * inv * ln1g[64 + lane] + ln1b[64 + lane];
    }
    __syncthreads();

    // ---------------- fused FFN tail ----------------
    // build a2: 16x136 bf16, row r mirrors hn[r&1]  (row 0 = node0, row 1 = node1)
#pragma unroll
    for (int it = 0; it < 2; ++it) {
        const int idx = it * 256 + tid;   // 0..511
        const int row = idx >> 5;
        const int c4  = idx & 31;
        const float4 v = *(const float4*)(hn + (row & 1) * 128 + c4 * 4);
        uint2 w;
        w.x = cvt_pk_bf16(v.x, v.y);
        w.y = cvt_pk_bf16(v.z, v.w);
        *(uint2*)(a2 + row * 136 + c4 * 4) = w;
    }
    __syncthreads();

    // GEMM-a: [16,128] @ Win^T -> gelu -> ff[16,512]; wave covers 128 FF cols
    {
        f32x4 accA[8];
#pragma unroll
        for (int i = 0; i < 8; ++i) accA[i] = zero;
#pragma unroll
        for (int s = 0; s < 4; ++s) {
            bf16x8 af = *(const bf16x8*)(a2 + c15 * 136 + s * 32 + q * 8);
#pragma unroll
            for (int nt = 0; nt < 8; ++nt) {
                const int n = wave * 128 + nt * 16 + c15;
                bf16x8 wb = *(const bf16x8*)(Winb + (size_t)n * 128 + s * 32 + q * 8);
                accA[nt] = mfma16(af, wb, accA[nt]);
            }
        }
#pragma unroll
        for (int nt = 0; nt < 8; ++nt) {
            const int colL = wave * 128 + nt * 16 + c15;
            const float bb = bin[colL];
#pragma unroll
            for (int r = 0; r < 4; ++r) {
                const int row = q * 4 + r;
                ff[row * 520 + colL] = f2bf(gelu_exact(accA[nt][r] + bb));
            }
        }
    }
    __syncthreads();

    // GEMM-b: ff[16,512] @ Wout^T -> accB; residual + bias -> tb (rows 0,1)
    {
        f32x4 accB[2]; accB[0] = zero; accB[1] = zero;
#pragma unroll
        for (int s = 0; s < 16; ++s) {
            bf16x8 af = *(const bf16x8*)(ff + c15 * 520 + s * 32 + q * 8);
#pragma unroll
            for (int nt = 0; nt < 2; ++nt) {
                const int n = wave * 32 + nt * 16 + c15;
                bf16x8 wb = *(const bf16x8*)(Woutb + (size_t)n * 512 + s * 32 + q * 8);
                accB[nt] = mfma16(af, wb, accB[nt]);
            }
        }
#pragma unroll
        for (int nt = 0; nt < 2; ++nt) {
            const int col = wave * 32 + nt * 16 + c15;
            const float bb = bout[col];
#pragma unroll
            for (int r = 0; r < 4; ++r) {
                const int row = q * 4 + r;
                if (row < 2)
                    tb[row * 132 + col] = accB[nt][r] + bb + hn[row * 128 + col];
            }
        }
    }
    __syncthreads();

    // LN2 + mask_V: wave w (w<2) handles node g0+w
    if (wave < 2) {
        const int row = wave;
        const float x0 = tb[row * 132 + lane];
        const float x1 = tb[row * 132 + 64 + lane];
        float sm = x0 + x1, sq = x0 * x0 + x1 * x1;
#pragma unroll
        for (int off = 1; off < 64; off <<= 1) { sm += __shfl_xor(sm, off); sq += __shfl_xor(sq, off); }
        const float mu  = sm * (1.0f / 128.0f);
        const float var = sq * (1.0f / 128.0f) - mu * mu;
        const float inv = rsqrtf(var + 1e-5f);
        const int g = g0 + row;
        const float mv = mask_V[g];
        out[(size_t)g * 128 + lane]      = mv * ((x0 - mu) * inv * ln2g[lane]      + ln2b[lane]);
        out[(size_t)g * 128 + 64 + lane] = mv * ((x1 - mu) * inv * ln2g[64 + lane] + ln2b[64 + lane]);
    }
}

// ---------------------------------------------------------------------------
extern "C" void kernel_launch(void* const* d_in, const int* in_sizes, int n_in,
                              void* d_out, int out_size, void* d_ws, size_t ws_size,
                              hipStream_t stream) {
    const float* h_V         = (const float*)d_in[0];
    const float* h_E         = (const float*)d_in[1];
    const float* mask_V      = (const float*)d_in[2];
    const float* mask_attend = (const float*)d_in[3];
    const float* W1w  = (const float*)d_in[4];
    const float* W1bb = (const float*)d_in[5];
    const float* W2w  = (const float*)d_in[6];
    const float* W2bb = (const float*)d_in[7];
    const float* W3w  = (const float*)d_in[8];
    const float* W3bb = (const float*)d_in[9];
    const float* ln1g = (const float*)d_in[10];
    const float* ln1b = (const float*)d_in[11];
    const float* ln2g = (const float*)d_in[12];
    const float* ln2b = (const float*)d_in[13];
    const float* Winw  = (const float*)d_in[14];
    const float* Winbb = (const float*)d_in[15];
    const float* Woutw  = (const float*)d_in[16];
    const float* Woutbb = (const float*)d_in[17];

    bf16* wsb   = (bf16*)d_ws;
    bf16* W1c   = wsb;
    bf16* W2c   = wsb + WS_W2;
    bf16* W3c   = wsb + WS_W3;
    bf16* Winc  = wsb + WS_WIN;
    bf16* Woutc = wsb + WS_WOUT;

    convert_weights<<<896, 256, 0, stream>>>(W1w, W2w, W3w, Winw, Woutw, wsb);
    msg_kernel<<<2048, 256, 0, stream>>>(h_V, h_E, mask_attend, W1c, W2c, W3c,
                                         W1bb, W2bb, W3bb, ln1g, ln1b,
                                         Winc, Woutc, Winbb, Woutbb,
                                         ln2g, ln2b, mask_V, (float*)d_out);
}

// Round 12
// 506.234 us; speedup vs baseline: 1.0212x; 1.0212x over previous
//
#include <hip/hip_runtime.h>
#include <math.h>

// ---------------------------------------------------------------------------
// DecoderLayer fused implementation (MI355X / gfx950)
//   K0: convert weights fp32 -> bf16 into ws
//   K1: per-node message MLP, 1 node/block (48 rows), 256 threads, 4096 blocks.
//       phase 1 REWRITTEN around global_load_lds (T3+T4):
//         - E/V tiles staged as fp32 [48 x 64] (12.3 KB), 3-deep rotation
//         - producer pre-swizzles the GLOBAL address (unit ^= row&7) so
//           consumer ds_read_b128 is bank-conflict-free; LDS dest stays linear
//         - W1 fragments via inline-asm global_load_dwordx4 (compiler emits
//           NO vmcnt waits); the only waits are manual counted vmcnt(7)
//         - raw s_barrier; GLOADs issued post-barrier (no DMA/read race)
//         - fp32->bf16 conversion at consume time (cvt_pk)
//   K2: FFN 512 blocks x 8 rows (R5 version, best measured).
// ---------------------------------------------------------------------------

typedef __bf16 bf16;
typedef __attribute__((ext_vector_type(8))) __bf16 bf16x8;
typedef __attribute__((ext_vector_type(4))) float f32x4;

__device__ __forceinline__ bf16 f2bf(float f) {
    unsigned u = __builtin_bit_cast(unsigned, f);
    u += 0x7FFFu + ((u >> 16) & 1u);           // RTNE
    unsigned short s = (unsigned short)(u >> 16);
    return __builtin_bit_cast(bf16, s);
}

__device__ __forceinline__ unsigned cvt_pk_bf16(float lo, float hi) {
    unsigned r;
    asm("v_cvt_pk_bf16_f32 %0, %1, %2" : "=v"(r) : "v"(lo), "v"(hi));
    return r;
}

// 8 consecutive fp32 (two float4) -> bf16x8 fragment
__device__ __forceinline__ bf16x8 mkfrag(float4 a, float4 b) {
    uint4 u;
    u.x = cvt_pk_bf16(a.x, a.y);
    u.y = cvt_pk_bf16(a.z, a.w);
    u.z = cvt_pk_bf16(b.x, b.y);
    u.w = cvt_pk_bf16(b.z, b.w);
    return __builtin_bit_cast(bf16x8, u);
}

__device__ __forceinline__ float gelu_exact(float x) {
    return 0.5f * x * (1.0f + erff(x * 0.70710678118654752f));
}

__device__ __forceinline__ f32x4 mfma16(bf16x8 a, bf16x8 b, f32x4 c) {
    return __builtin_amdgcn_mfma_f32_16x16x32_bf16(a, b, c, 0, 0, 0);
}

// async global->LDS, 16B per lane, LDS dest = uniform base + lane*16
template <typename T>
__device__ __forceinline__ void gld16(const T* src, void* dst) {
    __builtin_amdgcn_global_load_lds(
        (__attribute__((address_space(1))) void*)(src),
        (__attribute__((address_space(3))) void*)(dst), 16, 0, 0);
}

// ws layout (bf16 elements):
#define WS_W2   65536
#define WS_W3   81920
#define WS_WIN  98304
#define WS_WOUT 163840
#define WS_TOTAL_W 229376
#define WS_H1_BYTES 458752

// ---------------------------------------------------------------------------
__global__ void convert_weights(const float* __restrict__ W1, const float* __restrict__ W2,
                                const float* __restrict__ W3, const float* __restrict__ Win,
                                const float* __restrict__ Wout, bf16* __restrict__ ws) {
    int i = blockIdx.x * 256 + threadIdx.x;
    if (i < WS_W2)              ws[i] = f2bf(W1[i]);
    else if (i < WS_W3)         ws[i] = f2bf(W2[i - WS_W2]);
    else if (i < WS_WIN)        ws[i] = f2bf(W3[i - WS_W3]);
    else if (i < WS_WOUT)       ws[i] = f2bf(Win[i - WS_WIN]);
    else if (i < WS_TOTAL_W)    ws[i] = f2bf(Wout[i - WS_WOUT]);
}

// ---------------------------------------------------------------------------
// K1: 1 node per block (48 rows = 3 m-tiles), 256 threads (4 waves).
__global__ __launch_bounds__(256, 3)
void msg_kernel(const float* __restrict__ h_V, const float* __restrict__ h_E,
                const float* __restrict__ mask_attend,
                const bf16* __restrict__ W1b, const bf16* __restrict__ W2b,
                const bf16* __restrict__ W3b,
                const float* __restrict__ b1, const float* __restrict__ b2,
                const float* __restrict__ b3,
                const float* __restrict__ ln1g, const float* __restrict__ ln1b,
                float* __restrict__ h1out) {
    // LDS: st0/1/2 fp32 tiles 3x12288=36864 | m1 13056 @36864 | tbuf 512 @49920
    //      m2 (13056) aliases st0+st1. Total 50432 -> 3 blocks/CU.
    __shared__ __align__(16) char smem[50432];
    float* st0f = (float*)smem;
    float* st1f = (float*)(smem + 12288);
    float* st2f = (float*)(smem + 24576);
    bf16*  m2   = (bf16*)smem;              // aliases st0/st1 (dead in ph2+)
    bf16*  m1   = (bf16*)(smem + 36864);
    float* tbuf = (float*)(smem + 49920);

    const int tid  = threadIdx.x;
    const int wv   = tid >> 6;
    const int lane = tid & 63;
    const int q    = lane >> 4;      // quad 0..3
    const int c15  = lane & 15;
    const int g    = blockIdx.x;     // node id
    const int wcol0 = wv * 32 + c15;
    const int wcol1 = wcol0 + 16;

    f32x4 zero = {0.f, 0.f, 0.f, 0.f};
    f32x4 acc[3][2];
#pragma unroll
    for (int mt = 0; mt < 3; ++mt) { acc[mt][0] = zero; acc[mt][1] = zero; }

    // ---- producer: 12 chunks of 4 rows; wave w owns chunks 3w..3w+2.
    //      lane L -> row chunk*4 + L/16, unit L%16 (16B units, 16/row).
    //      slot (r,u) must hold source unit (u ^ (r&7))  [XOR swizzle]
#define GLOAD(bufbase_, kb_)                                                    \
    {                                                                           \
        _Pragma("unroll")                                                       \
        for (int i = 0; i < 3; ++i) {                                           \
            const int chunk_ = wv * 3 + i;                                      \
            const int r_  = chunk_ * 4 + (lane >> 4);                           \
            const int us_ = (lane & 15) ^ (r_ & 7);                             \
            const float* src_ = ((kb_) < 2)                                     \
                ? (h_V + (size_t)g * 128 + (kb_) * 64 + us_ * 4)                \
                : (h_E + (size_t)(g * 48 + r_) * 384 + ((kb_) - 2) * 64 + us_ * 4); \
            gld16(src_, (char*)(bufbase_) + chunk_ * 1024);                     \
        }                                                                       \
    }

    // ---- W1 fragments via inline asm (invisible to compiler's vmcnt model)
#define LDW_ASM(w0_, w1_, w2_, w3_, kb_)                                        \
    {                                                                           \
        const bf16* p0_ = W1b + (size_t)wcol0 * 512 + (kb_) * 64 + q * 8;       \
        const bf16* p2_ = W1b + (size_t)wcol1 * 512 + (kb_) * 64 + q * 8;       \
        asm volatile("global_load_dwordx4 %0, %1, off" : "=v"(w0_) : "v"(p0_)); \
        asm volatile("global_load_dwordx4 %0, %1, off" : "=v"(w1_) : "v"(p0_ + 32)); \
        asm volatile("global_load_dwordx4 %0, %1, off" : "=v"(w2_) : "v"(p2_)); \
        asm volatile("global_load_dwordx4 %0, %1, off" : "=v"(w3_) : "v"(p2_ + 32)); \
    }

    // ---- consumer: fp32 swizzled reads + cvt_pk + 12 MFMA
#define MFMA_STEP(base_, w0_, w1_, w2_, w3_)                                    \
    {                                                                           \
        _Pragma("unroll")                                                       \
        for (int mt = 0; mt < 3; ++mt) {                                        \
            const int row_ = mt * 16 + c15;                                     \
            const float* rp_ = (const float*)(base_) + row_ * 64;               \
            const int sw_ = row_ & 7;                                           \
            float4 fa_ = *(const float4*)(rp_ + (((q * 2)     ^ sw_) * 4));     \
            float4 fb_ = *(const float4*)(rp_ + (((q * 2 + 1) ^ sw_) * 4));     \
            float4 fc_ = *(const float4*)(rp_ + (((8 + q * 2)     ^ sw_) * 4)); \
            float4 fd_ = *(const float4*)(rp_ + (((8 + q * 2 + 1) ^ sw_) * 4)); \
            bf16x8 a0_ = mkfrag(fa_, fb_);                                      \
            bf16x8 a1_ = mkfrag(fc_, fd_);                                      \
            acc[mt][0] = mfma16(a0_, w0_, acc[mt][0]);                          \
            acc[mt][0] = mfma16(a1_, w1_, acc[mt][0]);                          \
            acc[mt][1] = mfma16(a0_, w2_, acc[mt][1]);                          \
            acc[mt][1] = mfma16(a1_, w3_, acc[mt][1]);                          \
        }                                                                       \
    }

#define WAITV(N) { asm volatile("s_waitcnt vmcnt(" #N ")" ::: "memory"); \
                   __builtin_amdgcn_sched_barrier(0); }
#define BAR() __builtin_amdgcn_s_barrier()

    // ---------------- phase 1: 8 K-64 tiles, 3-deep LDS rotation -------------
    // per-wave vmcnt queue at WAITV of step k (oldest..newest):
    //   [gl(k)=3, W(k)=4, gl(k+1)=3, W(k+1)=4]  -> wait 7 drains gl(k)+W(k),
    //   leaves gl(k+1)+W(k+1) in flight (~2 steps of latency cover).
    // GLOAD(k+2) issues POST-barrier so DMA can't race other waves' reads.
    {
        bf16x8 wc0, wc1, wc2, wc3, wn0, wn1, wn2, wn3;

        LDW_ASM(wc0, wc1, wc2, wc3, 0);
        GLOAD(st0f, 0);
        GLOAD(st1f, 1);
        // step 0
        LDW_ASM(wn0, wn1, wn2, wn3, 1);
        WAITV(7);  BAR();  GLOAD(st2f, 2);
        MFMA_STEP(st0f, wc0, wc1, wc2, wc3);
        // step 1
        LDW_ASM(wc0, wc1, wc2, wc3, 2);
        WAITV(7);  BAR();  GLOAD(st0f, 3);
        MFMA_STEP(st1f, wn0, wn1, wn2, wn3);
        // step 2
        LDW_ASM(wn0, wn1, wn2, wn3, 3);
        WAITV(7);  BAR();  GLOAD(st1f, 4);
        MFMA_STEP(st2f, wc0, wc1, wc2, wc3);
        // step 3
        LDW_ASM(wc0, wc1, wc2, wc3, 4);
        WAITV(7);  BAR();  GLOAD(st2f, 5);
        MFMA_STEP(st0f, wn0, wn1, wn2, wn3);
        // step 4
        LDW_ASM(wn0, wn1, wn2, wn3, 5);
        WAITV(7);  BAR();  GLOAD(st0f, 6);
        MFMA_STEP(st1f, wc0, wc1, wc2, wc3);
        // step 5
        LDW_ASM(wc0, wc1, wc2, wc3, 6);
        WAITV(7);  BAR();  GLOAD(st1f, 7);
        MFMA_STEP(st2f, wn0, wn1, wn2, wn3);
        // step 6
        LDW_ASM(wn0, wn1, wn2, wn3, 7);
        WAITV(7);  BAR();
        MFMA_STEP(st0f, wc0, wc1, wc2, wc3);
        // step 7
        WAITV(0);  BAR();
        MFMA_STEP(st1f, wn0, wn1, wn2, wn3);
    }
#undef BAR
#undef WAITV
#undef MFMA_STEP
#undef LDW_ASM
#undef GLOAD

    // epilogue 1: bias + gelu -> m1   (C/D layout: row = q*4+reg, col = c15)
    {
        const float bb0 = b1[wcol0];
        const float bb1 = b1[wcol1];
#pragma unroll
        for (int mt = 0; mt < 3; ++mt) {
#pragma unroll
            for (int r = 0; r < 4; ++r) {
                const int row = mt * 16 + q * 4 + r;
                m1[row * 136 + wcol0] = f2bf(gelu_exact(acc[mt][0][r] + bb0));
                m1[row * 136 + wcol1] = f2bf(gelu_exact(acc[mt][1][r] + bb1));
            }
        }
    }
    __syncthreads();

    // ---------------- phase 2 ----------------
#pragma unroll
    for (int mt = 0; mt < 3; ++mt) { acc[mt][0] = zero; acc[mt][1] = zero; }
#pragma unroll
    for (int s = 0; s < 4; ++s) {
        const bf16x8 w0 = *(const bf16x8*)(W2b + (size_t)wcol0 * 128 + s * 32 + q * 8);
        const bf16x8 w1 = *(const bf16x8*)(W2b + (size_t)wcol1 * 128 + s * 32 + q * 8);
#pragma unroll
        for (int mt = 0; mt < 3; ++mt) {
            bf16x8 af = *(const bf16x8*)(m1 + (mt * 16 + c15) * 136 + s * 32 + q * 8);
            acc[mt][0] = mfma16(af, w0, acc[mt][0]);
            acc[mt][1] = mfma16(af, w1, acc[mt][1]);
        }
    }
    {
        const float bb0 = b2[wcol0];
        const float bb1 = b2[wcol1];
#pragma unroll
        for (int mt = 0; mt < 3; ++mt) {
#pragma unroll
            for (int r = 0; r < 4; ++r) {
                const int row = mt * 16 + q * 4 + r;
                m2[row * 136 + wcol0] = f2bf(gelu_exact(acc[mt][0][r] + bb0));
                m2[row * 136 + wcol1] = f2bf(gelu_exact(acc[mt][1][r] + bb1));
            }
        }
    }
    __syncthreads();

    // ---------------- phase 3 ----------------
#pragma unroll
    for (int mt = 0; mt < 3; ++mt) { acc[mt][0] = zero; acc[mt][1] = zero; }
#pragma unroll
    for (int s = 0; s < 4; ++s) {
        const bf16x8 w0 = *(const bf16x8*)(W3b + (size_t)wcol0 * 128 + s * 32 + q * 8);
        const bf16x8 w1 = *(const bf16x8*)(W3b + (size_t)wcol1 * 128 + s * 32 + q * 8);
#pragma unroll
        for (int mt = 0; mt < 3; ++mt) {
            bf16x8 af = *(const bf16x8*)(m2 + (mt * 16 + c15) * 136 + s * 32 + q * 8);
            acc[mt][0] = mfma16(af, w0, acc[mt][0]);
            acc[mt][1] = mfma16(af, w1, acc[mt][1]);
        }
    }
    // masked sum over the node's 48 edges
    {
        const float bb0 = b3[wcol0];
        const float bb1 = b3[wcol1];
        float s0 = 0.f, s1 = 0.f;
#pragma unroll
        for (int mt = 0; mt < 3; ++mt) {
#pragma unroll
            for (int r = 0; r < 4; ++r) {
                const int row = mt * 16 + q * 4 + r;
                const float mv = mask_attend[(size_t)g * 48 + row];
                s0 += (acc[mt][0][r] + bb0) * mv;
                s1 += (acc[mt][1][r] + bb1) * mv;
            }
        }
#pragma unroll
        for (int off = 16; off <= 32; off <<= 1) {
            s0 += __shfl_xor(s0, off);
            s1 += __shfl_xor(s1, off);
        }
        if (lane < 16) {
            tbuf[wcol0] = h_V[(size_t)g * 128 + wcol0] + s0 * (1.0f / 30.0f);
            tbuf[wcol1] = h_V[(size_t)g * 128 + wcol1] + s1 * (1.0f / 30.0f);
        }
    }
    __syncthreads();
    // LN1: wave 0 handles the node
    if (wv == 0) {
        const float x0 = tbuf[lane];
        const float x1 = tbuf[64 + lane];
        float sm = x0 + x1, sq = x0 * x0 + x1 * x1;
#pragma unroll
        for (int off = 1; off < 64; off <<= 1) { sm += __shfl_xor(sm, off); sq += __shfl_xor(sq, off); }
        const float mu  = sm * (1.0f / 128.0f);
        const float var = sq * (1.0f / 128.0f) - mu * mu;
        const float inv = rsqrtf(var + 1e-5f);
        h1out[(size_t)g * 128 + lane]      = (x0 - mu) * inv * ln1g[lane]      + ln1b[lane];
        h1out[(size_t)g * 128 + 64 + lane] = (x1 - mu) * inv * ln1g[64 + lane] + ln1b[64 + lane];
    }
}

// ---------------------------------------------------------------------------
// K2: FFN + LN2 + mask_V. 8 rows per block, 512 blocks, 256 threads. (R5)
__global__ __launch_bounds__(256, 4)
void ffn_kernel(const float* __restrict__ h1, const bf16* __restrict__ Winb,
                const bf16* __restrict__ Woutb,
                const float* __restrict__ bin, const float* __restrict__ bout,
                const float* __restrict__ ln2g, const float* __restrict__ ln2b,
                const float* __restrict__ mask_V, float* __restrict__ out) {
    __shared__ __align__(16) bf16  a2[16 * 136];   // rows 8..15 = copy of 0..7
    __shared__ __align__(16) bf16  ff[16 * 520];
    __shared__ __align__(16) float tb[8 * 132];

    const int tid  = threadIdx.x;
    const int wave = tid >> 6;
    const int lane = tid & 63;
    const int q    = lane >> 4;
    const int c15  = lane & 15;
    const int r0g  = blockIdx.x * 8;

    {
        const int row = tid >> 5;
        const int c4  = tid & 31;
        const float4 v = *(const float4*)(h1 + (size_t)(r0g + row) * 128 + c4 * 4);
        uint2 w;
        w.x = cvt_pk_bf16(v.x, v.y);
        w.y = cvt_pk_bf16(v.z, v.w);
        *(uint2*)(a2 + row * 136 + c4 * 4)       = w;
        *(uint2*)(a2 + (row + 8) * 136 + c4 * 4) = w;
    }
    __syncthreads();

    f32x4 zero = {0.f, 0.f, 0.f, 0.f};

    f32x4 accA[8];
#pragma unroll
    for (int i = 0; i < 8; ++i) accA[i] = zero;
    __builtin_amdgcn_s_setprio(1);
#pragma unroll
    for (int s = 0; s < 4; ++s) {
        bf16x8 af = *(const bf16x8*)(a2 + c15 * 136 + s * 32 + q * 8);
#pragma unroll
        for (int nt = 0; nt < 8; ++nt) {
            const int n = wave * 128 + nt * 16 + c15;
            bf16x8 wb = *(const bf16x8*)(Winb + (size_t)n * 128 + s * 32 + q * 8);
            accA[nt] = mfma16(af, wb, accA[nt]);
        }
    }
    __builtin_amdgcn_s_setprio(0);
#pragma unroll
    for (int nt = 0; nt < 8; ++nt) {
        const int colL = wave * 128 + nt * 16 + c15;
        const float bb = bin[colL];
#pragma unroll
        for (int r = 0; r < 4; ++r) {
            const int row = q * 4 + r;
            ff[row * 520 + colL] = f2bf(gelu_exact(accA[nt][r] + bb));
        }
    }
    __syncthreads();

    f32x4 accB[2]; accB[0] = zero; accB[1] = zero;
    __builtin_amdgcn_s_setprio(1);
#pragma unroll
    for (int s = 0; s < 16; ++s) {
        bf16x8 af = *(const bf16x8*)(ff + c15 * 520 + s * 32 + q * 8);
#pragma unroll
        for (int nt = 0; nt < 2; ++nt) {
            const int n = wave * 32 + nt * 16 + c15;
            bf16x8 wb = *(const bf16x8*)(Woutb + (size_t)n * 512 + s * 32 + q * 8);
            accB[nt] = mfma16(af, wb, accB[nt]);
        }
    }
    __builtin_amdgcn_s_setprio(0);

#pragma unroll
    for (int nt = 0; nt < 2; ++nt) {
        const int col = wave * 32 + nt * 16 + c15;
        const float bb = bout[col];
#pragma unroll
        for (int r = 0; r < 4; ++r) {
            const int row = q * 4 + r;
            if (row < 8)
                tb[row * 132 + col] = accB[nt][r] + bb + h1[(size_t)(r0g + row) * 128 + col];
        }
    }
    __syncthreads();

#pragma unroll
    for (int rr = 0; rr < 2; ++rr) {
        const int row = wave * 2 + rr;
        const float x0 = tb[row * 132 + lane];
        const float x1 = tb[row * 132 + 64 + lane];
        float sm = x0 + x1, sq = x0 * x0 + x1 * x1;
#pragma unroll
        for (int off = 1; off < 64; off <<= 1) { sm += __shfl_xor(sm, off); sq += __shfl_xor(sq, off); }
        const float mu  = sm * (1.0f / 128.0f);
        const float var = sq * (1.0f / 128.0f) - mu * mu;
        const float inv = rsqrtf(var + 1e-5f);
        const int g = r0g + row;
        const float mv = mask_V[g];
        out[(size_t)g * 128 + lane]      = mv * ((x0 - mu) * inv * ln2g[lane]      + ln2b[lane]);
        out[(size_t)g * 128 + 64 + lane] = mv * ((x1 - mu) * inv * ln2g[64 + lane] + ln2b[64 + lane]);
    }
}

// ---------------------------------------------------------------------------
extern "C" void kernel_launch(void* const* d_in, const int* in_sizes, int n_in,
                              void* d_out, int out_size, void* d_ws, size_t ws_size,
                              hipStream_t stream) {
    const float* h_V         = (const float*)d_in[0];
    const float* h_E         = (const float*)d_in[1];
    const float* mask_V      = (const float*)d_in[2];
    const float* mask_attend = (const float*)d_in[3];
    const float* W1w  = (const float*)d_in[4];
    const float* W1bb = (const float*)d_in[5];
    const float* W2w  = (const float*)d_in[6];
    const float* W2bb = (const float*)d_in[7];
    const float* W3w  = (const float*)d_in[8];
    const float* W3bb = (const float*)d_in[9];
    const float* ln1g = (const float*)d_in[10];
    const float* ln1b = (const float*)d_in[11];
    const float* ln2g = (const float*)d_in[12];
    const float* ln2b = (const float*)d_in[13];
    const float* Winw  = (const float*)d_in[14];
    const float* Winbb = (const float*)d_in[15];
    const float* Woutw  = (const float*)d_in[16];
    const float* Woutbb = (const float*)d_in[17];

    bf16* wsb   = (bf16*)d_ws;
    bf16* W1c   = wsb;
    bf16* W2c   = wsb + WS_W2;
    bf16* W3c   = wsb + WS_W3;
    bf16* Winc  = wsb + WS_WIN;
    bf16* Woutc = wsb + WS_WOUT;
    float* h1   = (float*)((char*)d_ws + WS_H1_BYTES);

    convert_weights<<<896, 256, 0, stream>>>(W1w, W2w, W3w, Winw, Woutw, wsb);
    msg_kernel<<<4096, 256, 0, stream>>>(h_V, h_E, mask_attend, W1c, W2c, W3c,
                                         W1bb, W2bb, W3bb, ln1g, ln1b, h1);
    ffn_kernel<<<512, 256, 0, stream>>>(h1, Winc, Woutc, Winbb, Woutbb,
                                        ln2g, ln2b, mask_V, (float*)d_out);
}

// Round 13
// 479.476 us; speedup vs baseline: 1.0782x; 1.0558x over previous
//
#include <hip/hip_runtime.h>
#include <math.h>

// ---------------------------------------------------------------------------
// DecoderLayer fused implementation (MI355X / gfx950)
//   K0: convert weights fp32 -> bf16 into ws
//   K0b: hv_bias = h_V @ W1V^T  ([4096,128]@[128,128], fp32 out) -- the h_V
//        part of phase-1 is identical for all 48 edges of a node, so it is
//        computed ONCE per node here instead of per-edge in msg.
//   K1: per-node message MLP, 2 nodes/block, 256 threads, 2048 blocks.
//       phase 1 now SIX K-steps (h_E only, K=384); acc initialized from
//       hv_bias. Pipeline mechanics identical to R5 (best measured): LDS
//       dbuf staging, 1 raw s_barrier/step, W-before-E issue order, setprio.
//   K2: FFN 512 blocks x 8 rows (R5 version, best measured).
// ---------------------------------------------------------------------------

typedef __bf16 bf16;
typedef __attribute__((ext_vector_type(8))) __bf16 bf16x8;
typedef __attribute__((ext_vector_type(4))) float f32x4;

__device__ __forceinline__ bf16 f2bf(float f) {
    unsigned u = __builtin_bit_cast(unsigned, f);
    u += 0x7FFFu + ((u >> 16) & 1u);           // RTNE
    unsigned short s = (unsigned short)(u >> 16);
    return __builtin_bit_cast(bf16, s);
}

__device__ __forceinline__ unsigned cvt_pk_bf16(float lo, float hi) {
    unsigned r;
    asm("v_cvt_pk_bf16_f32 %0, %1, %2" : "=v"(r) : "v"(lo), "v"(hi));
    return r;
}

__device__ __forceinline__ float gelu_exact(float x) {
    return 0.5f * x * (1.0f + erff(x * 0.70710678118654752f));
}

__device__ __forceinline__ f32x4 mfma16(bf16x8 a, bf16x8 b, f32x4 c) {
    return __builtin_amdgcn_mfma_f32_16x16x32_bf16(a, b, c, 0, 0, 0);
}

// ws layout:
//   bf16 weights: W1b@0 (65536) W2b@65536 W3b@81920 Winb@98304 Woutb@163840
//   h1   @ byte 458752 : 4096*128 fp32 = 2 MB
//   hvb  @ byte 2555904: 4096*128 fp32 = 2 MB   (h_V @ W1V^T)
#define WS_W2   65536
#define WS_W3   81920
#define WS_WIN  98304
#define WS_WOUT 163840
#define WS_TOTAL_W 229376
#define WS_H1_BYTES 458752
#define WS_HVB_BYTES 2555904

// ---------------------------------------------------------------------------
__global__ void convert_weights(const float* __restrict__ W1, const float* __restrict__ W2,
                                const float* __restrict__ W3, const float* __restrict__ Win,
                                const float* __restrict__ Wout, bf16* __restrict__ ws) {
    int i = blockIdx.x * 256 + threadIdx.x;
    if (i < WS_W2)              ws[i] = f2bf(W1[i]);
    else if (i < WS_W3)         ws[i] = f2bf(W2[i - WS_W2]);
    else if (i < WS_WIN)        ws[i] = f2bf(W3[i - WS_W3]);
    else if (i < WS_WOUT)       ws[i] = f2bf(Win[i - WS_WIN]);
    else if (i < WS_TOTAL_W)    ws[i] = f2bf(Wout[i - WS_WOUT]);
}

// ---------------------------------------------------------------------------
// K0b: hvb[g][o] = sum_k h_V[g][k] * W1[o][k]  (k<128 part of W1)
//   16 rows/block, 256 blocks, 256 threads; wave wv covers cols wv*32..+31.
__global__ __launch_bounds__(256, 4)
void hv_bias_kernel(const float* __restrict__ h_V, const bf16* __restrict__ W1b,
                    float* __restrict__ hvb) {
    __shared__ __align__(16) bf16 a2[16 * 136];

    const int tid  = threadIdx.x;
    const int wave = tid >> 6;
    const int lane = tid & 63;
    const int q    = lane >> 4;
    const int c15  = lane & 15;
    const int r0g  = blockIdx.x * 16;

    // stage 16 h_V rows -> bf16 LDS
#pragma unroll
    for (int it = 0; it < 2; ++it) {
        const int idx = it * 256 + tid;      // 0..511 float4s
        const int row = idx >> 5;
        const int c4  = idx & 31;
        const float4 v = *(const float4*)(h_V + (size_t)(r0g + row) * 128 + c4 * 4);
        uint2 w;
        w.x = cvt_pk_bf16(v.x, v.y);
        w.y = cvt_pk_bf16(v.z, v.w);
        *(uint2*)(a2 + row * 136 + c4 * 4) = w;
    }
    __syncthreads();

    f32x4 zero = {0.f, 0.f, 0.f, 0.f};
    f32x4 acc[2]; acc[0] = zero; acc[1] = zero;
#pragma unroll
    for (int s = 0; s < 4; ++s) {
        bf16x8 af = *(const bf16x8*)(a2 + c15 * 136 + s * 32 + q * 8);
#pragma unroll
        for (int nt = 0; nt < 2; ++nt) {
            const int n = wave * 32 + nt * 16 + c15;
            bf16x8 wb = *(const bf16x8*)(W1b + (size_t)n * 512 + s * 32 + q * 8);
            acc[nt] = mfma16(af, wb, acc[nt]);
        }
    }
#pragma unroll
    for (int nt = 0; nt < 2; ++nt) {
        const int n = wave * 32 + nt * 16 + c15;
#pragma unroll
        for (int r = 0; r < 4; ++r) {
            const int row = q * 4 + r;
            hvb[(size_t)(r0g + row) * 128 + n] = acc[nt][r];
        }
    }
}

// ---------------------------------------------------------------------------
// K1: 2 nodes per block (M = 96 edge rows), 256 threads (4 waves).
__global__ __launch_bounds__(256, 3)
void msg_kernel(const float* __restrict__ h_V, const float* __restrict__ h_E,
                const float* __restrict__ mask_attend,
                const bf16* __restrict__ W1b, const bf16* __restrict__ W2b,
                const bf16* __restrict__ W3b,
                const float* __restrict__ b1, const float* __restrict__ b2,
                const float* __restrict__ b3,
                const float* __restrict__ ln1g, const float* __restrict__ ln1b,
                const float* __restrict__ hvb,
                float* __restrict__ h1out) {
    // LDS: stage dbuf 2x13824 = 27648 | m1 26112  (total 53760 -> 3 blocks/CU)
    //      m2 (26112) aliases the stage dbuf; tbuf (1024) aliases m1.
    __shared__ __align__(16) char smem[53760];
    bf16*  st0  = (bf16*)smem;              // 96 x 72
    bf16*  st1  = (bf16*)(smem + 13824);    // 96 x 72
    bf16*  m2   = (bf16*)smem;              // 96 x 136 (aliases st0+st1)
    bf16*  m1   = (bf16*)(smem + 27648);    // 96 x 136
    float* tbuf = (float*)(smem + 27648);   // 256 fp32 (aliases m1)

    const int tid  = threadIdx.x;
    const int wave = tid >> 6;
    const int lane = tid & 63;
    const int q    = lane >> 4;     // quad 0..3
    const int c15  = lane & 15;
    const int g0   = blockIdx.x * 2;  // first node of this block
    const int wcol0 = wave * 32 + c15;
    const int wcol1 = wcol0 + 16;

    const int r0  = tid >> 4;   // staging row within 16-row group
    const int l16 = tid & 15;   // staging float4 index

    // hv-bias scalars (oldest loads: waiting on them never drains E/W)
    const float t00 = hvb[(size_t)g0 * 128 + wcol0];
    const float t01 = hvb[(size_t)g0 * 128 + wcol1];
    const float t10 = hvb[(size_t)(g0 + 1) * 128 + wcol0];
    const float t11 = hvb[(size_t)(g0 + 1) * 128 + wcol1];

    f32x4 acc[6][2];
#pragma unroll
    for (int mt = 0; mt < 6; ++mt) {
        const float a0 = (mt < 3) ? t00 : t10;
        const float a1 = (mt < 3) ? t01 : t11;
        acc[mt][0] = (f32x4){a0, a0, a0, a0};
        acc[mt][1] = (f32x4){a1, a1, a1, a1};
    }
    f32x4 zero = {0.f, 0.f, 0.f, 0.f};

    // kb = 0..5 -> h_E cols kb*64 .. +63
#define STAGE_LOAD(dst_, kb_)                                                   \
    {                                                                           \
        _Pragma("unroll")                                                       \
        for (int it = 0; it < 6; ++it) {                                        \
            const int row_ = it * 16 + r0;                                      \
            const int nl_  = row_ >= 48;                                        \
            const float* src_ = h_E + (size_t)((g0 + nl_) * 48 + row_ - 48 * nl_) * 384 \
                                     + (kb_) * 64 + l16 * 4;                    \
            dst_[it] = *(const float4*)src_;                                    \
        }                                                                       \
    }

#define STAGE_WRITE(buf_, src_)                                                 \
    {                                                                           \
        _Pragma("unroll")                                                       \
        for (int it = 0; it < 6; ++it) {                                        \
            const int row_ = it * 16 + r0;                                      \
            uint2 w_;                                                           \
            w_.x = cvt_pk_bf16(src_[it].x, src_[it].y);                         \
            w_.y = cvt_pk_bf16(src_[it].z, src_[it].w);                         \
            *(uint2*)((buf_) + row_ * 72 + l16 * 4) = w_;                       \
        }                                                                       \
    }

    // W1E part: k offset 128 + kb*64
#define LD_W(w00_, w01_, w10_, w11_, kb_)                                       \
    {                                                                           \
        w00_ = *(const bf16x8*)(W1b + (size_t)wcol0 * 512 + 128 + (kb_) * 64 + q * 8);      \
        w01_ = *(const bf16x8*)(W1b + (size_t)wcol0 * 512 + 128 + (kb_) * 64 + 32 + q * 8); \
        w10_ = *(const bf16x8*)(W1b + (size_t)wcol1 * 512 + 128 + (kb_) * 64 + q * 8);      \
        w11_ = *(const bf16x8*)(W1b + (size_t)wcol1 * 512 + 128 + (kb_) * 64 + 32 + q * 8); \
    }

#define MFMA_STEP(stb_, w00_, w01_, w10_, w11_)                                 \
    {                                                                           \
        __builtin_amdgcn_s_setprio(1);                                          \
        _Pragma("unroll")                                                       \
        for (int mt = 0; mt < 6; ++mt) {                                        \
            bf16x8 a0_ = *(const bf16x8*)((stb_) + (mt * 16 + c15) * 72 + q * 8);      \
            bf16x8 a1_ = *(const bf16x8*)((stb_) + (mt * 16 + c15) * 72 + 32 + q * 8); \
            acc[mt][0] = mfma16(a0_, w00_, acc[mt][0]);                         \
            acc[mt][0] = mfma16(a1_, w01_, acc[mt][0]);                         \
            acc[mt][1] = mfma16(a0_, w10_, acc[mt][1]);                         \
            acc[mt][1] = mfma16(a1_, w11_, acc[mt][1]);                         \
        }                                                                       \
        __builtin_amdgcn_s_setprio(0);                                          \
    }

    // raw barrier: drain only LDS ops; global loads stay in flight (no vmcnt!)
#define BAR() { asm volatile("s_waitcnt lgkmcnt(0)" ::: "memory"); __builtin_amdgcn_s_barrier(); }

    // ---------------- phase 1: 6 K-steps over h_E ----------------
    {
        float4 rA[6], rB[6];
        bf16x8 wc0, wc1, wc2, wc3, wn0, wn1, wn2, wn3;

        STAGE_LOAD(rA, 0);              // E(0)
        LD_W(wc0, wc1, wc2, wc3, 0);    // W(0)  (before E(1))
        STAGE_LOAD(rB, 1);              // E(1)
        STAGE_WRITE(st0, rA);           // waits E(0) only
        BAR();
        // step 0
        LD_W(wn0, wn1, wn2, wn3, 1);
        STAGE_LOAD(rA, 2);
        MFMA_STEP(st0, wc0, wc1, wc2, wc3);
        STAGE_WRITE(st1, rB);
        BAR();
        // step 1
        LD_W(wc0, wc1, wc2, wc3, 2);
        STAGE_LOAD(rB, 3);
        MFMA_STEP(st1, wn0, wn1, wn2, wn3);
        STAGE_WRITE(st0, rA);
        BAR();
        // step 2
        LD_W(wn0, wn1, wn2, wn3, 3);
        STAGE_LOAD(rA, 4);
        MFMA_STEP(st0, wc0, wc1, wc2, wc3);
        STAGE_WRITE(st1, rB);
        BAR();
        // step 3
        LD_W(wc0, wc1, wc2, wc3, 4);
        STAGE_LOAD(rB, 5);
        MFMA_STEP(st1, wn0, wn1, wn2, wn3);
        STAGE_WRITE(st0, rA);
        BAR();
        // step 4 (no more E tiles)
        LD_W(wn0, wn1, wn2, wn3, 5);
        MFMA_STEP(st0, wc0, wc1, wc2, wc3);
        STAGE_WRITE(st1, rB);
        BAR();
        // step 5
        MFMA_STEP(st1, wn0, wn1, wn2, wn3);
    }
#undef BAR
#undef MFMA_STEP
#undef LD_W
#undef STAGE_WRITE
#undef STAGE_LOAD

    // epilogue 1: bias + gelu -> m1   (C/D layout: row = q*4+reg, col = c15)
    {
        const float bb0 = b1[wcol0];
        const float bb1 = b1[wcol1];
#pragma unroll
        for (int mt = 0; mt < 6; ++mt) {
#pragma unroll
            for (int r = 0; r < 4; ++r) {
                const int row = mt * 16 + q * 4 + r;
                m1[row * 136 + wcol0] = f2bf(gelu_exact(acc[mt][0][r] + bb0));
                m1[row * 136 + wcol1] = f2bf(gelu_exact(acc[mt][1][r] + bb1));
            }
        }
    }
    __syncthreads();

    // ---------------- phase 2 ----------------
#pragma unroll
    for (int mt = 0; mt < 6; ++mt) { acc[mt][0] = zero; acc[mt][1] = zero; }
    __builtin_amdgcn_s_setprio(1);
#pragma unroll
    for (int s = 0; s < 4; ++s) {
        const bf16x8 w0 = *(const bf16x8*)(W2b + (size_t)wcol0 * 128 + s * 32 + q * 8);
        const bf16x8 w1 = *(const bf16x8*)(W2b + (size_t)wcol1 * 128 + s * 32 + q * 8);
#pragma unroll
        for (int mt = 0; mt < 6; ++mt) {
            bf16x8 af = *(const bf16x8*)(m1 + (mt * 16 + c15) * 136 + s * 32 + q * 8);
            acc[mt][0] = mfma16(af, w0, acc[mt][0]);
            acc[mt][1] = mfma16(af, w1, acc[mt][1]);
        }
    }
    __builtin_amdgcn_s_setprio(0);
    {
        const float bb0 = b2[wcol0];
        const float bb1 = b2[wcol1];
#pragma unroll
        for (int mt = 0; mt < 6; ++mt) {
#pragma unroll
            for (int r = 0; r < 4; ++r) {
                const int row = mt * 16 + q * 4 + r;
                m2[row * 136 + wcol0] = f2bf(gelu_exact(acc[mt][0][r] + bb0));
                m2[row * 136 + wcol1] = f2bf(gelu_exact(acc[mt][1][r] + bb1));
            }
        }
    }
    __syncthreads();

    // ---------------- phase 3 ----------------
#pragma unroll
    for (int mt = 0; mt < 6; ++mt) { acc[mt][0] = zero; acc[mt][1] = zero; }
    __builtin_amdgcn_s_setprio(1);
#pragma unroll
    for (int s = 0; s < 4; ++s) {
        const bf16x8 w0 = *(const bf16x8*)(W3b + (size_t)wcol0 * 128 + s * 32 + q * 8);
        const bf16x8 w1 = *(const bf16x8*)(W3b + (size_t)wcol1 * 128 + s * 32 + q * 8);
#pragma unroll
        for (int mt = 0; mt < 6; ++mt) {
            bf16x8 af = *(const bf16x8*)(m2 + (mt * 16 + c15) * 136 + s * 32 + q * 8);
            acc[mt][0] = mfma16(af, w0, acc[mt][0]);
            acc[mt][1] = mfma16(af, w1, acc[mt][1]);
        }
    }
    __builtin_amdgcn_s_setprio(0);
    // masked sum over edges
    {
        const float bb0 = b3[wcol0];
        const float bb1 = b3[wcol1];
        float s00 = 0.f, s01 = 0.f, s10 = 0.f, s11 = 0.f;
#pragma unroll
        for (int mt = 0; mt < 6; ++mt) {
#pragma unroll
            for (int r = 0; r < 4; ++r) {
                const int row = mt * 16 + q * 4 + r;
                const int nl  = row >= 48;
                const float mv = mask_attend[(size_t)(g0 + nl) * 48 + row - 48 * nl];
                const float v0 = (acc[mt][0][r] + bb0) * mv;
                const float v1 = (acc[mt][1][r] + bb1) * mv;
                if (nl) { s10 += v0; s11 += v1; } else { s00 += v0; s01 += v1; }
            }
        }
#pragma unroll
        for (int off = 16; off <= 32; off <<= 1) {
            s00 += __shfl_xor(s00, off);
            s01 += __shfl_xor(s01, off);
            s10 += __shfl_xor(s10, off);
            s11 += __shfl_xor(s11, off);
        }
        if (lane < 16) {
            tbuf[wcol0]       = h_V[(size_t)g0 * 128 + wcol0]       + s00 * (1.0f / 30.0f);
            tbuf[wcol1]       = h_V[(size_t)g0 * 128 + wcol1]       + s01 * (1.0f / 30.0f);
            tbuf[128 + wcol0] = h_V[(size_t)(g0 + 1) * 128 + wcol0] + s10 * (1.0f / 30.0f);
            tbuf[128 + wcol1] = h_V[(size_t)(g0 + 1) * 128 + wcol1] + s11 * (1.0f / 30.0f);
        }
    }
    __syncthreads();
    // LN1: wave 0 -> node0, wave 1 -> node1
    if (wave < 2) {
        const float x0 = tbuf[wave * 128 + lane];
        const float x1 = tbuf[wave * 128 + 64 + lane];
        float sm = x0 + x1, sq = x0 * x0 + x1 * x1;
#pragma unroll
        for (int off = 1; off < 64; off <<= 1) { sm += __shfl_xor(sm, off); sq += __shfl_xor(sq, off); }
        const float mu  = sm * (1.0f / 128.0f);
        const float var = sq * (1.0f / 128.0f) - mu * mu;
        const float inv = rsqrtf(var + 1e-5f);
        const int g = g0 + wave;
        h1out[(size_t)g * 128 + lane]      = (x0 - mu) * inv * ln1g[lane]      + ln1b[lane];
        h1out[(size_t)g * 128 + 64 + lane] = (x1 - mu) * inv * ln1g[64 + lane] + ln1b[64 + lane];
    }
}

// ---------------------------------------------------------------------------
// K2: FFN + LN2 + mask_V. 8 rows per block, 512 blocks, 256 threads. (R5)
__global__ __launch_bounds__(256, 4)
void ffn_kernel(const float* __restrict__ h1, const bf16* __restrict__ Winb,
                const bf16* __restrict__ Woutb,
                const float* __restrict__ bin, const float* __restrict__ bout,
                const float* __restrict__ ln2g, const float* __restrict__ ln2b,
                const float* __restrict__ mask_V, float* __restrict__ out) {
    __shared__ __align__(16) bf16  a2[16 * 136];   // rows 8..15 = copy of 0..7
    __shared__ __align__(16) bf16  ff[16 * 520];
    __shared__ __align__(16) float tb[8 * 132];

    const int tid  = threadIdx.x;
    const int wave = tid >> 6;
    const int lane = tid & 63;
    const int q    = lane >> 4;
    const int c15  = lane & 15;
    const int r0g  = blockIdx.x * 8;

    {
        const int row = tid >> 5;
        const int c4  = tid & 31;
        const float4 v = *(const float4*)(h1 + (size_t)(r0g + row) * 128 + c4 * 4);
        uint2 w;
        w.x = cvt_pk_bf16(v.x, v.y);
        w.y = cvt_pk_bf16(v.z, v.w);
        *(uint2*)(a2 + row * 136 + c4 * 4)       = w;
        *(uint2*)(a2 + (row + 8) * 136 + c4 * 4) = w;
    }
    __syncthreads();

    f32x4 zero = {0.f, 0.f, 0.f, 0.f};

    f32x4 accA[8];
#pragma unroll
    for (int i = 0; i < 8; ++i) accA[i] = zero;
    __builtin_amdgcn_s_setprio(1);
#pragma unroll
    for (int s = 0; s < 4; ++s) {
        bf16x8 af = *(const bf16x8*)(a2 + c15 * 136 + s * 32 + q * 8);
#pragma unroll
        for (int nt = 0; nt < 8; ++nt) {
            const int n = wave * 128 + nt * 16 + c15;
            bf16x8 wb = *(const bf16x8*)(Winb + (size_t)n * 128 + s * 32 + q * 8);
            accA[nt] = mfma16(af, wb, accA[nt]);
        }
    }
    __builtin_amdgcn_s_setprio(0);
#pragma unroll
    for (int nt = 0; nt < 8; ++nt) {
        const int colL = wave * 128 + nt * 16 + c15;
        const float bb = bin[colL];
#pragma unroll
        for (int r = 0; r < 4; ++r) {
            const int row = q * 4 + r;
            ff[row * 520 + colL] = f2bf(gelu_exact(accA[nt][r] + bb));
        }
    }
    __syncthreads();

    f32x4 accB[2]; accB[0] = zero; accB[1] = zero;
    __builtin_amdgcn_s_setprio(1);
#pragma unroll
    for (int s = 0; s < 16; ++s) {
        bf16x8 af = *(const bf16x8*)(ff + c15 * 520 + s * 32 + q * 8);
#pragma unroll
        for (int nt = 0; nt < 2; ++nt) {
            const int n = wave * 32 + nt * 16 + c15;
            bf16x8 wb = *(const bf16x8*)(Woutb + (size_t)n * 512 + s * 32 + q * 8);
            accB[nt] = mfma16(af, wb, accB[nt]);
        }
    }
    __builtin_amdgcn_s_setprio(0);

#pragma unroll
    for (int nt = 0; nt < 2; ++nt) {
        const int col = wave * 32 + nt * 16 + c15;
        const float bb = bout[col];
#pragma unroll
        for (int r = 0; r < 4; ++r) {
            const int row = q * 4 + r;
            if (row < 8)
                tb[row * 132 + col] = accB[nt][r] + bb + h1[(size_t)(r0g + row) * 128 + col];
        }
    }
    __syncthreads();

#pragma unroll
    for (int rr = 0; rr < 2; ++rr) {
        const int row = wave * 2 + rr;
        const float x0 = tb[row * 132 + lane];
        const float x1 = tb[row * 132 + 64 + lane];
        float sm = x0 + x1, sq = x0 * x0 + x1 * x1;
#pragma unroll
        for (int off = 1; off < 64; off <<= 1) { sm += __shfl_xor(sm, off); sq += __shfl_xor(sq, off); }
        const float mu  = sm * (1.0f / 128.0f);
        const float var = sq * (1.0f / 128.0f) - mu * mu;
        const float inv = rsqrtf(var + 1e-5f);
        const int g = r0g + row;
        const float mv = mask_V[g];
        out[(size_t)g * 128 + lane]      = mv * ((x0 - mu) * inv * ln2g[lane]      + ln2b[lane]);
        out[(size_t)g * 128 + 64 + lane] = mv * ((x1 - mu) * inv * ln2g[64 + lane] + ln2b[64 + lane]);
    }
}

// ---------------------------------------------------------------------------
extern "C" void kernel_launch(void* const* d_in, const int* in_sizes, int n_in,
                              void* d_out, int out_size, void* d_ws, size_t ws_size,
                              hipStream_t stream) {
    const float* h_V         = (const float*)d_in[0];
    const float* h_E         = (const float*)d_in[1];
    const float* mask_V      = (const float*)d_in[2];
    const float* mask_attend = (const float*)d_in[3];
    const float* W1w  = (const float*)d_in[4];
    const float* W1bb = (const float*)d_in[5];
    const float* W2w  = (const float*)d_in[6];
    const float* W2bb = (const float*)d_in[7];
    const float* W3w  = (const float*)d_in[8];
    const float* W3bb = (const float*)d_in[9];
    const float* ln1g = (const float*)d_in[10];
    const float* ln1b = (const float*)d_in[11];
    const float* ln2g = (const float*)d_in[12];
    const float* ln2b = (const float*)d_in[13];
    const float* Winw  = (const float*)d_in[14];
    const float* Winbb = (const float*)d_in[15];
    const float* Woutw  = (const float*)d_in[16];
    const float* Woutbb = (const float*)d_in[17];

    bf16* wsb   = (bf16*)d_ws;
    bf16* W1c   = wsb;
    bf16* W2c   = wsb + WS_W2;
    bf16* W3c   = wsb + WS_W3;
    bf16* Winc  = wsb + WS_WIN;
    bf16* Woutc = wsb + WS_WOUT;
    float* h1   = (float*)((char*)d_ws + WS_H1_BYTES);
    float* hvb  = (float*)((char*)d_ws + WS_HVB_BYTES);

    convert_weights<<<896, 256, 0, stream>>>(W1w, W2w, W3w, Winw, Woutw, wsb);
    hv_bias_kernel<<<256, 256, 0, stream>>>(h_V, W1c, hvb);
    msg_kernel<<<2048, 256, 0, stream>>>(h_V, h_E, mask_attend, W1c, W2c, W3c,
                                         W1bb, W2bb, W3bb, ln1g, ln1b, hvb, h1);
    ffn_kernel<<<512, 256, 0, stream>>>(h1, Winc, Woutc, Winbb, Woutbb,
                                        ln2g, ln2b, mask_V, (float*)d_out);
}